// Round 2
// baseline (1541.895 us; speedup 1.0000x reference)
//
#include <hip/hip_runtime.h>
#include <hip/hip_bf16.h>
#include <math.h>

typedef __bf16 bf16x8_t __attribute__((ext_vector_type(8)));
typedef float f32x4_t __attribute__((ext_vector_type(4)));
typedef __hip_bfloat16 bf16;

// async global -> LDS, 16B per lane, wave-uniform LDS base + lane*16
__device__ __forceinline__ void gload_lds16(const bf16* gsrc, unsigned short* ldst) {
  __builtin_amdgcn_global_load_lds(
      (const __attribute__((address_space(1))) unsigned int*)gsrc,
      (__attribute__((address_space(3))) unsigned int*)ldst, 16, 0, 0);
}

// ---------------- fp32 -> bf16 convert ----------------
__global__ __launch_bounds__(256) void f2b_kernel(const float* __restrict__ in,
                                                  bf16* __restrict__ out, size_t n) {
  size_t i = ((size_t)blockIdx.x * 256 + threadIdx.x) * 4;
  if (i + 4 <= n) {
    float4 v = *reinterpret_cast<const float4*>(in + i);
    union { bf16 b[4]; ushort4 u; } cv;
    cv.b[0] = __float2bfloat16(v.x);
    cv.b[1] = __float2bfloat16(v.y);
    cv.b[2] = __float2bfloat16(v.z);
    cv.b[3] = __float2bfloat16(v.w);
    *reinterpret_cast<ushort4*>(out + i) = cv.u;
  } else {
    for (; i < n; ++i) out[i] = __float2bfloat16(in[i]);
  }
}

// ---------------- fp32 [K][N] -> bf16 transposed [N][K] ----------------
__global__ __launch_bounds__(256) void transpose_f2b_kernel(const float* __restrict__ in,
                                                            bf16* __restrict__ out,
                                                            int K, int N) {
  __shared__ float t[32][33];
  int n0 = blockIdx.x * 32, k0 = blockIdx.y * 32;
  int tx = threadIdx.x & 31, ty = threadIdx.x >> 5;  // 32 x 8
#pragma unroll
  for (int i = 0; i < 32; i += 8)
    t[ty + i][tx] = in[(size_t)(k0 + ty + i) * N + n0 + tx];
  __syncthreads();
#pragma unroll
  for (int i = 0; i < 32; i += 8)
    out[(size_t)(n0 + ty + i) * K + k0 + tx] = __float2bfloat16(t[tx][ty + i]);
}

// ---------------- RMSNorm (fp32 in -> bf16 out) ----------------
__global__ __launch_bounds__(256) void rmsnorm_kernel(const float* __restrict__ in,
                                                      const float* __restrict__ w,
                                                      bf16* __restrict__ out, int C) {
  int row = blockIdx.x;
  const float* r = in + (size_t)row * C;
  int tid = threadIdx.x;
  float ss = 0.f;
  for (int c = tid; c < C; c += 256) { float v = r[c]; ss += v * v; }
#pragma unroll
  for (int o = 32; o > 0; o >>= 1) ss += __shfl_down(ss, o, 64);
  __shared__ float part[4];
  if ((tid & 63) == 0) part[tid >> 6] = ss;
  __syncthreads();
  float inv = rsqrtf((part[0] + part[1] + part[2] + part[3]) / (float)C + 1e-6f);
  bf16* orow = out + (size_t)row * C;
  for (int c = tid; c < C; c += 256) orow[c] = __float2bfloat16(r[c] * inv * w[c]);
}

// ---------------- gather: pad + roll(-shift), split channels ----------------
__global__ __launch_bounds__(256) void gather_kernel(const bf16* __restrict__ xi,
                                                     bf16* __restrict__ xb,
                                                     int Tp, int Tn, int shift, int coff) {
  size_t i = (size_t)blockIdx.x * 256 + threadIdx.x;  // over B*Tp*256
  int c = (int)(i & 255);
  size_t bt = i >> 8;
  int t = (int)(bt % (size_t)Tp);
  int b = (int)(bt / (size_t)Tp);
  int src = t + shift; if (src >= Tp) src -= Tp;
  bf16 v = __float2bfloat16(0.f);
  if (src < Tn) v = xi[(((size_t)b * Tn + src) << 9) + coff + c];
  xb[i] = v;
}

// ---------------- per-window attention (fp32 math, bf16 qkv in / bf16 out) ----
template <int W, int SHIFT>
__global__ void attn_kernel(const bf16* __restrict__ qkv, const float* __restrict__ rpb,
                            bf16* __restrict__ out, int nW, int Tp) {
  int blk = blockIdx.x;
  int b = blk / nW, n = blk % nW;
  int pair = threadIdx.x;
  if (pair >= 8 * W) return;
  int h = pair / W, qi = pair % W;
  size_t base = ((size_t)b * Tp + (size_t)n * W) * 768;
  float qv[32];
#pragma unroll
  for (int d = 0; d < 32; ++d) qv[d] = __bfloat162float(qkv[base + (size_t)qi * 768 + h * 32 + d]);
  const float scale = 0.17677669529663689f;
  float sc[W];
  float mx = -1e30f;
  for (int k = 0; k < W; ++k) {
    const bf16* kr = qkv + base + (size_t)k * 768 + 256 + h * 32;
    float dot = 0.f;
#pragma unroll
    for (int d = 0; d < 32; ++d) dot += qv[d] * __bfloat162float(kr[d]);
    float s = dot * scale + rpb[(qi - k + W - 1) * 8 + h];
    if (n == nW - 1) {
      bool lq = qi < (W - SHIFT), lk = k < (W - SHIFT);
      if (lq != lk) s -= 100.0f;
    }
    sc[k] = s;
    mx = fmaxf(mx, s);
  }
  float l = 0.f;
  for (int k = 0; k < W; ++k) { sc[k] = expf(sc[k] - mx); l += sc[k]; }
  float inv = 1.0f / l;
  float ov[32];
#pragma unroll
  for (int d = 0; d < 32; ++d) ov[d] = 0.f;
  for (int k = 0; k < W; ++k) {
    const bf16* vr = qkv + base + (size_t)k * 768 + 512 + h * 32;
    float p = sc[k];
#pragma unroll
    for (int d = 0; d < 32; ++d) ov[d] += p * __bfloat162float(vr[d]);
  }
  bf16* orow = out + ((size_t)b * Tp + (size_t)n * W + qi) * 256 + h * 32;
#pragma unroll
  for (int d = 0; d < 32; ++d) orow[d] = __float2bfloat16(ov[d] * inv);
}

// ---------------- 128x128 MFMA GEMM: C = A(MxK) @ Wt^T + bias --------------
// A: [M][K] bf16 row-major.  Wt: [N][K] bf16 row-major (pre-transposed weight).
// BK=32, 4 waves, each computes 64x64 (4x4 frags of 16x16x32).
// T1: bijective XCD block swizzle (m204).
// T4: 3-deep triple-buffered prefetch, counted s_waitcnt vmcnt(8) (never 0 in
//     steady state) -> load latency covered by ~2.5 K-steps.
// T2: LDS chunk swizzle chunk' = chunk ^ ((row>>1)&3), applied BOTH sides:
//     inverse-swizzled global SOURCE column in stage (LDS dest stays linear,
//     as required by global_load_lds) + swizzled read address. 8-way -> 2-way.
// T5: s_setprio(1) around the MFMA cluster.
// MODE 0: fp32 out   MODE 1: bf16 out
// MODE 2: fp32 out = acc + bias + resid  (resid may alias outF)
// MODE 3: bf16 out = gelu_exact(acc + bias)
// MODE 5: bf16 scatter, inverse roll: row (b,t') -> out[b, (t'+shift)%Tp] if < Tn, col+coff
template <int MODE>
__global__ __launch_bounds__(256) void gemm_kernel(
    const bf16* __restrict__ A, const bf16* __restrict__ Wt,
    const float* __restrict__ bias,
    float* outF, bf16* outB, const float* resid,
    int M, int N, int K, int ldc, int Tp, int Tn, int shift, int coff) {
  __shared__ unsigned short lA[3][128 * 32];
  __shared__ unsigned short lB[3][128 * 32];
  int tid = threadIdx.x;
  int wave = tid >> 6, lane = tid & 63;

  // ---- T1: bijective XCD-aware swizzle of the flat block id (m204) ----
  int nx = gridDim.x;
  int nwg = nx * gridDim.y;
  int id = blockIdx.y * nx + blockIdx.x;
  int q = nwg >> 3, r = nwg & 7;
  int xcd = id & 7, pos = id >> 3;
  int swz = (xcd < r ? xcd * (q + 1) : r * (q + 1) + (xcd - r) * q) + pos;
  int bx = swz % nx, by = swz / nx;

  int m0 = by * 128, n0 = bx * 128;
  int wm = (wave >> 1) * 64, wn = (wave & 1) * 64;
  int ml = lane & 15, cc = lane >> 4;  // cc = logical 16B chunk (k-offset/8)
  f32x4_t acc[4][4] = {};

  int lrow = lane >> 2;        // 0..15 (row within a 16-row chunk)
  int pchunk = lane & 3;       // physical 16B chunk this lane fills

  // stage one 32-row slice per wave of both A and B tiles into buffer `buf`.
  // source column inverse-swizzled so that a swizzled READ sees logical data.
  auto stage = [&](int buf, int k0) {
#pragma unroll
    for (int j = 0; j < 2; ++j) {
      int rr = wave * 32 + j * 16;     // wave-uniform LDS row base
      int row = rr + lrow;             // this lane's row in tile (0..127)
      int scol = (pchunk ^ ((row >> 1) & 3)) * 8;  // inverse swizzle
      int gr = m0 + row; if (gr > M - 1) gr = M - 1;  // clamp; masked at store
      gload_lds16(A + (size_t)gr * K + k0 + scol, &lA[buf][rr * 32]);
      int nr = n0 + row;  // N is a multiple of 128 for all our GEMMs
      gload_lds16(Wt + (size_t)nr * K + k0 + scol, &lB[buf][rr * 32]);
    }
  };
  auto compute = [&](int buf) {
    const unsigned short* sA = lA[buf];
    const unsigned short* sB = lB[buf];
    bf16x8_t fa[4], fb[4];
#pragma unroll
    for (int t = 0; t < 4; ++t) {
      int ra = wm + t * 16 + ml;
      fa[t] = *reinterpret_cast<const bf16x8_t*>(&sA[ra * 32 + ((cc ^ ((ra >> 1) & 3)) << 3)]);
      int rb = wn + t * 16 + ml;
      fb[t] = *reinterpret_cast<const bf16x8_t*>(&sB[rb * 32 + ((cc ^ ((rb >> 1) & 3)) << 3)]);
    }
    __builtin_amdgcn_s_setprio(1);
#pragma unroll
    for (int mt = 0; mt < 4; ++mt)
#pragma unroll
      for (int nt = 0; nt < 4; ++nt)
        acc[mt][nt] = __builtin_amdgcn_mfma_f32_16x16x32_bf16(fa[mt], fb[nt], acc[mt][nt], 0, 0, 0);
    __builtin_amdgcn_s_setprio(0);
  };

  // K >= 256 and K % 32 == 0 for every GEMM in this net -> NT >= 8.
  int NT = K >> 5;
  stage(0, 0);
  stage(1, 32);
  stage(2, 64);
  int cur = 0;
  for (int t = 0; t < NT; ++t) {
    int rem = NT - 1 - t;  // tiles staged after this one still outstanding
    if (rem >= 2)      asm volatile("s_waitcnt vmcnt(8)" ::: "memory");
    else if (rem == 1) asm volatile("s_waitcnt vmcnt(4)" ::: "memory");
    else               asm volatile("s_waitcnt vmcnt(0)" ::: "memory");
    __builtin_amdgcn_s_barrier();          // tile t fully landed for all waves
    compute(cur);
    __builtin_amdgcn_s_barrier();          // all waves done reading tile t
    if (t + 3 < NT) stage(cur, (t + 3) * 32);
    cur = cur + 1; if (cur == 3) cur = 0;
  }

  int rbase = (lane >> 4) * 4;
#pragma unroll
  for (int mt = 0; mt < 4; ++mt)
#pragma unroll
    for (int nt = 0; nt < 4; ++nt)
#pragma unroll
      for (int i = 0; i < 4; ++i) {
        int row = m0 + wm + mt * 16 + rbase + i;
        int col = n0 + wn + nt * 16 + ml;
        if (row >= M) continue;
        float v = acc[mt][nt][i] + bias[col];
        if (MODE == 0) {
          outF[(size_t)row * ldc + col] = v;
        } else if (MODE == 1) {
          outB[(size_t)row * ldc + col] = __float2bfloat16(v);
        } else if (MODE == 2) {
          outF[(size_t)row * ldc + col] = v + resid[(size_t)row * ldc + col];
        } else if (MODE == 3) {
          v = 0.5f * v * (1.0f + erff(v * 0.70710678118654752f));
          outB[(size_t)row * ldc + col] = __float2bfloat16(v);
        } else if (MODE == 5) {
          int b = row / Tp;
          int t = row - b * Tp;
          int i2 = t + shift; if (i2 >= Tp) i2 -= Tp;
          if (i2 < Tn)
            outB[((size_t)b * Tn + i2) * ldc + coff + col] = __float2bfloat16(v);
        }
      }
}

extern "C" void kernel_launch(void* const* d_in, const int* in_sizes, int n_in,
                              void* d_out, int out_size, void* d_ws, size_t ws_size,
                              hipStream_t stream) {
  const float* x       = (const float*)d_in[0];
  const float* down_w  = (const float*)d_in[1];
  const float* down_b  = (const float*)d_in[2];
  const float* up_w    = (const float*)d_in[3];
  const float* up_b    = (const float*)d_in[4];
  const float* norm1_w = (const float*)d_in[5];
  const float* norm2_w = (const float*)d_in[6];
  const float* qkv1_w  = (const float*)d_in[7];
  const float* qkv1_b  = (const float*)d_in[8];
  const float* proj1_w = (const float*)d_in[9];
  const float* proj1_b = (const float*)d_in[10];
  const float* rpb1    = (const float*)d_in[11];
  const float* qkv2_w  = (const float*)d_in[12];
  const float* qkv2_b  = (const float*)d_in[13];
  const float* proj2_w = (const float*)d_in[14];
  const float* proj2_b = (const float*)d_in[15];
  const float* rpb2    = (const float*)d_in[16];
  const float* ffn_w1  = (const float*)d_in[17];
  const float* ffn_b1  = (const float*)d_in[18];
  const float* ffn_w2  = (const float*)d_in[19];
  const float* ffn_b2  = (const float*)d_in[20];
  float* out = (float*)d_out;

  const int Bb = 8, T = 4096, DIM = 1024, DIM_IN = 512;
  const int Tp = 4100, Tn = T;
  const int M  = Bb * T;   // 32768
  const int Mp = Bb * Tp;  // 32800
  const int nW1 = Tp / 10, nW2 = Tp / 20;

  char* ws = (char*)d_ws;
  const size_t MB = 1ull << 20;
  size_t wo = 0;
  auto walloc = [&](size_t elems) {
    bf16* p = (bf16*)(ws + wo);
    wo += ((elems * 2 + 255) & ~(size_t)255);
    return p;
  };
  // transposed bf16 weights [N][K]
  bf16* w_down  = walloc(1024 * 512);
  bf16* w_up    = walloc(512 * 1024);
  bf16* w_qkv1  = walloc(256 * 768);
  bf16* w_proj1 = walloc(256 * 256);
  bf16* w_qkv2  = walloc(256 * 768);
  bf16* w_proj2 = walloc(256 * 256);
  bf16* w_ffn1  = walloc(1024 * 2048);
  bf16* w_ffn2  = walloc(2048 * 1024);
  // overlapped scratch:
  bf16*  xbf     = (bf16*)(ws + 12 * MB);   // x bf16 (down gemm only)
  bf16*  xb1     = (bf16*)(ws + 12 * MB);   // after xbf dead
  bf16*  xb2     = (bf16*)(ws + 29 * MB);
  bf16*  att1    = (bf16*)(ws + 46 * MB);
  bf16*  att2    = (bf16*)(ws + 63 * MB);
  float* y1      = (float*)(ws + 80 * MB);  // down fp32 out
  bf16*  concatb = (bf16*)(ws + 80 * MB);   // after y1 dead
  bf16*  hbuf    = (bf16*)(ws + 80 * MB);   // after concat dead
  bf16*  xi      = (bf16*)(ws + 144 * MB);
  bf16*  qkv1buf = (bf16*)(ws + 176 * MB);
  bf16*  qkv2buf = (bf16*)(ws + 225 * MB);
  bf16*  gbuf    = (bf16*)(ws + 144 * MB);  // after xi/qkv dead

  auto cvt = [&](const float* src, bf16* dst, size_t n) {
    int grid = (int)((n / 4 + 255) / 256);
    hipLaunchKernelGGL(f2b_kernel, dim3(grid), dim3(256), 0, stream, src, dst, n);
  };
  auto tr = [&](const float* src, bf16* dst, int K, int N) {
    hipLaunchKernelGGL(transpose_f2b_kernel, dim3(N / 32, K / 32), dim3(256), 0, stream,
                       src, dst, K, N);
  };
  cvt(x, xbf, (size_t)M * DIM);
  tr(down_w, w_down, 1024, 512);
  tr(up_w, w_up, 512, 1024);
  tr(qkv1_w, w_qkv1, 256, 768);
  tr(proj1_w, w_proj1, 256, 256);
  tr(qkv2_w, w_qkv2, 256, 768);
  tr(proj2_w, w_proj2, 256, 256);
  tr(ffn_w1, w_ffn1, 1024, 2048);
  tr(ffn_w2, w_ffn2, 2048, 1024);

  auto gemm = [&](auto modeTag, const bf16* A, const bf16* Wt, const float* bias,
                  float* oF, bf16* oB, const float* res,
                  int Mm, int Nn, int Kk, int ldc, int tp, int tn, int sh, int co) {
    constexpr int MODE = decltype(modeTag)::value;
    hipLaunchKernelGGL((gemm_kernel<MODE>), dim3(Nn / 128, (Mm + 127) / 128), dim3(256), 0,
                       stream, A, Wt, bias, oF, oB, res, Mm, Nn, Kk, ldc, tp, tn, sh, co);
  };
  using I0 = std::integral_constant<int, 0>;
  using I1 = std::integral_constant<int, 1>;
  using I2 = std::integral_constant<int, 2>;
  using I3 = std::integral_constant<int, 3>;
  using I5 = std::integral_constant<int, 5>;

  // down: y1 = x @ down_w + down_b (fp32)
  gemm(I0{}, xbf, w_down, down_b, y1, nullptr, nullptr, M, DIM_IN, DIM, DIM_IN, 0, 0, 0, 0);
  hipLaunchKernelGGL(rmsnorm_kernel, dim3(M), dim3(256), 0, stream, y1, norm1_w, xi, DIM_IN);
  hipLaunchKernelGGL(gather_kernel, dim3(Mp), dim3(256), 0, stream, xi, xb1, Tp, Tn, 5, 0);
  hipLaunchKernelGGL(gather_kernel, dim3(Mp), dim3(256), 0, stream, xi, xb2, Tp, Tn, 10, 256);
  gemm(I1{}, xb1, w_qkv1, qkv1_b, nullptr, qkv1buf, nullptr, Mp, 768, 256, 768, 0, 0, 0, 0);
  gemm(I1{}, xb2, w_qkv2, qkv2_b, nullptr, qkv2buf, nullptr, Mp, 768, 256, 768, 0, 0, 0, 0);
  hipLaunchKernelGGL((attn_kernel<10, 5>), dim3(Bb * nW1), dim3(128), 0, stream,
                     qkv1buf, rpb1, att1, nW1, Tp);
  hipLaunchKernelGGL((attn_kernel<20, 10>), dim3(Bb * nW2), dim3(192), 0, stream,
                     qkv2buf, rpb2, att2, nW2, Tp);
  gemm(I5{}, att1, w_proj1, proj1_b, nullptr, concatb, nullptr, Mp, 256, 256, 512, Tp, Tn, 5, 0);
  gemm(I5{}, att2, w_proj2, proj2_b, nullptr, concatb, nullptr, Mp, 256, 256, 512, Tp, Tn, 10, 256);
  // up: out = x + concat @ up_w + up_b (fp32, xnew)
  gemm(I2{}, concatb, w_up, up_b, out, nullptr, x, M, DIM, DIM_IN, DIM, 0, 0, 0, 0);
  hipLaunchKernelGGL(rmsnorm_kernel, dim3(M), dim3(256), 0, stream, out, norm2_w, hbuf, DIM);
  gemm(I3{}, hbuf, w_ffn1, ffn_b1, nullptr, gbuf, nullptr, M, 2048, DIM, 2048, 0, 0, 0, 0);
  gemm(I2{}, gbuf, w_ffn2, ffn_b2, out, nullptr, out, M, DIM, 2048, DIM, 0, 0, 0, 0);
  (void)in_sizes; (void)n_in; (void)out_size; (void)ws_size;
}

// Round 3
// 1408.144 us; speedup vs baseline: 1.0950x; 1.0950x over previous
//
#include <hip/hip_runtime.h>
#include <hip/hip_bf16.h>
#include <math.h>
#include <type_traits>

typedef __bf16 bf16x8_t __attribute__((ext_vector_type(8)));
typedef float f32x4_t __attribute__((ext_vector_type(4)));
typedef __hip_bfloat16 bf16;

// async global -> LDS, 16B per lane, wave-uniform LDS base + lane*16
__device__ __forceinline__ void gload_lds16(const bf16* gsrc, unsigned short* ldst) {
  __builtin_amdgcn_global_load_lds(
      (const __attribute__((address_space(1))) unsigned int*)gsrc,
      (__attribute__((address_space(3))) unsigned int*)ldst, 16, 0, 0);
}

// ---------------- fp32 -> bf16 convert ----------------
__global__ __launch_bounds__(256) void f2b_kernel(const float* __restrict__ in,
                                                  bf16* __restrict__ out, size_t n) {
  size_t i = ((size_t)blockIdx.x * 256 + threadIdx.x) * 4;
  if (i + 4 <= n) {
    float4 v = *reinterpret_cast<const float4*>(in + i);
    union { bf16 b[4]; ushort4 u; } cv;
    cv.b[0] = __float2bfloat16(v.x);
    cv.b[1] = __float2bfloat16(v.y);
    cv.b[2] = __float2bfloat16(v.z);
    cv.b[3] = __float2bfloat16(v.w);
    *reinterpret_cast<ushort4*>(out + i) = cv.u;
  } else {
    for (; i < n; ++i) out[i] = __float2bfloat16(in[i]);
  }
}

// ---------------- fp32 [K][N] -> bf16 transposed [N][K] ----------------
__global__ __launch_bounds__(256) void transpose_f2b_kernel(const float* __restrict__ in,
                                                            bf16* __restrict__ out,
                                                            int K, int N) {
  __shared__ float t[32][33];
  int n0 = blockIdx.x * 32, k0 = blockIdx.y * 32;
  int tx = threadIdx.x & 31, ty = threadIdx.x >> 5;  // 32 x 8
#pragma unroll
  for (int i = 0; i < 32; i += 8)
    t[ty + i][tx] = in[(size_t)(k0 + ty + i) * N + n0 + tx];
  __syncthreads();
#pragma unroll
  for (int i = 0; i < 32; i += 8)
    out[(size_t)(n0 + ty + i) * K + k0 + tx] = __float2bfloat16(t[tx][ty + i]);
}

// ---------------- RMSNorm (fp32 in -> bf16 out) ----------------
__global__ __launch_bounds__(256) void rmsnorm_kernel(const float* __restrict__ in,
                                                      const float* __restrict__ w,
                                                      bf16* __restrict__ out, int C) {
  int row = blockIdx.x;
  const float* r = in + (size_t)row * C;
  int tid = threadIdx.x;
  float ss = 0.f;
  for (int c = tid; c < C; c += 256) { float v = r[c]; ss += v * v; }
#pragma unroll
  for (int o = 32; o > 0; o >>= 1) ss += __shfl_down(ss, o, 64);
  __shared__ float part[4];
  if ((tid & 63) == 0) part[tid >> 6] = ss;
  __syncthreads();
  float inv = rsqrtf((part[0] + part[1] + part[2] + part[3]) / (float)C + 1e-6f);
  bf16* orow = out + (size_t)row * C;
  for (int c = tid; c < C; c += 256) orow[c] = __float2bfloat16(r[c] * inv * w[c]);
}

// ---------------- gather: pad + roll(-shift), split channels ----------------
__global__ __launch_bounds__(256) void gather_kernel(const bf16* __restrict__ xi,
                                                     bf16* __restrict__ xb,
                                                     int Tp, int Tn, int shift, int coff) {
  size_t i = (size_t)blockIdx.x * 256 + threadIdx.x;  // over B*Tp*256
  int c = (int)(i & 255);
  size_t bt = i >> 8;
  int t = (int)(bt % (size_t)Tp);
  int b = (int)(bt / (size_t)Tp);
  int src = t + shift; if (src >= Tp) src -= Tp;
  bf16 v = __float2bfloat16(0.f);
  if (src < Tn) v = xi[(((size_t)b * Tn + src) << 9) + coff + c];
  xb[i] = v;
}

// ---------------- per-window attention (fp32 math, bf16 qkv in / bf16 out) ----
template <int W, int SHIFT>
__global__ void attn_kernel(const bf16* __restrict__ qkv, const float* __restrict__ rpb,
                            bf16* __restrict__ out, int nW, int Tp) {
  int blk = blockIdx.x;
  int b = blk / nW, n = blk % nW;
  int pair = threadIdx.x;
  if (pair >= 8 * W) return;
  int h = pair / W, qi = pair % W;
  size_t base = ((size_t)b * Tp + (size_t)n * W) * 768;
  float qv[32];
#pragma unroll
  for (int d = 0; d < 32; ++d) qv[d] = __bfloat162float(qkv[base + (size_t)qi * 768 + h * 32 + d]);
  const float scale = 0.17677669529663689f;
  float sc[W];
  float mx = -1e30f;
  for (int k = 0; k < W; ++k) {
    const bf16* kr = qkv + base + (size_t)k * 768 + 256 + h * 32;
    float dot = 0.f;
#pragma unroll
    for (int d = 0; d < 32; ++d) dot += qv[d] * __bfloat162float(kr[d]);
    float s = dot * scale + rpb[(qi - k + W - 1) * 8 + h];
    if (n == nW - 1) {
      bool lq = qi < (W - SHIFT), lk = k < (W - SHIFT);
      if (lq != lk) s -= 100.0f;
    }
    sc[k] = s;
    mx = fmaxf(mx, s);
  }
  float l = 0.f;
  for (int k = 0; k < W; ++k) { sc[k] = expf(sc[k] - mx); l += sc[k]; }
  float inv = 1.0f / l;
  float ov[32];
#pragma unroll
  for (int d = 0; d < 32; ++d) ov[d] = 0.f;
  for (int k = 0; k < W; ++k) {
    const bf16* vr = qkv + base + (size_t)k * 768 + 512 + h * 32;
    float p = sc[k];
#pragma unroll
    for (int d = 0; d < 32; ++d) ov[d] += p * __bfloat162float(vr[d]);
  }
  bf16* orow = out + ((size_t)b * Tp + (size_t)n * W + qi) * 256 + h * 32;
#pragma unroll
  for (int d = 0; d < 32; ++d) orow[d] = __float2bfloat16(ov[d] * inv);
}

// ======================= 128x128 GEMM (small shapes: qkv, proj) =============
// Verified R2 kernel: T1 swizzle + 3-deep counted vmcnt + chunk-XOR LDS swizzle.
// MODE 1: bf16 out   MODE 5: bf16 scatter with inverse roll
template <int MODE>
__global__ __launch_bounds__(256) void gemm_kernel(
    const bf16* __restrict__ A, const bf16* __restrict__ Wt,
    const float* __restrict__ bias,
    float* outF, bf16* outB, const float* resid,
    int M, int N, int K, int ldc, int Tp, int Tn, int shift, int coff) {
  __shared__ unsigned short lA[3][128 * 32];
  __shared__ unsigned short lB[3][128 * 32];
  int tid = threadIdx.x;
  int wave = tid >> 6, lane = tid & 63;

  int nx = gridDim.x;
  int nwg = nx * gridDim.y;
  int id = blockIdx.y * nx + blockIdx.x;
  int q = nwg >> 3, r = nwg & 7;
  int xcd = id & 7, pos = id >> 3;
  int swz = (xcd < r ? xcd * (q + 1) : r * (q + 1) + (xcd - r) * q) + pos;
  int bx = swz % nx, by = swz / nx;

  int m0 = by * 128, n0 = bx * 128;
  int wm = (wave >> 1) * 64, wn = (wave & 1) * 64;
  int ml = lane & 15, cc = lane >> 4;
  f32x4_t acc[4][4] = {};

  int lrow = lane >> 2;
  int pchunk = lane & 3;

  auto stage = [&](int buf, int k0) {
#pragma unroll
    for (int j = 0; j < 2; ++j) {
      int rr = wave * 32 + j * 16;
      int row = rr + lrow;
      int scol = (pchunk ^ ((row >> 1) & 3)) * 8;
      int gr = m0 + row; if (gr > M - 1) gr = M - 1;
      gload_lds16(A + (size_t)gr * K + k0 + scol, &lA[buf][rr * 32]);
      int nr = n0 + row;
      gload_lds16(Wt + (size_t)nr * K + k0 + scol, &lB[buf][rr * 32]);
    }
  };
  auto compute = [&](int buf) {
    const unsigned short* sA = lA[buf];
    const unsigned short* sB = lB[buf];
    bf16x8_t fa[4], fb[4];
#pragma unroll
    for (int t = 0; t < 4; ++t) {
      int ra = wm + t * 16 + ml;
      fa[t] = *reinterpret_cast<const bf16x8_t*>(&sA[ra * 32 + ((cc ^ ((ra >> 1) & 3)) << 3)]);
      int rb = wn + t * 16 + ml;
      fb[t] = *reinterpret_cast<const bf16x8_t*>(&sB[rb * 32 + ((cc ^ ((rb >> 1) & 3)) << 3)]);
    }
    __builtin_amdgcn_s_setprio(1);
#pragma unroll
    for (int mt = 0; mt < 4; ++mt)
#pragma unroll
      for (int nt = 0; nt < 4; ++nt)
        acc[mt][nt] = __builtin_amdgcn_mfma_f32_16x16x32_bf16(fa[mt], fb[nt], acc[mt][nt], 0, 0, 0);
    __builtin_amdgcn_s_setprio(0);
  };

  int NT = K >> 5;
  stage(0, 0);
  stage(1, 32);
  stage(2, 64);
  int cur = 0;
  for (int t = 0; t < NT; ++t) {
    int rem = NT - 1 - t;
    if (rem >= 2)      asm volatile("s_waitcnt vmcnt(8)" ::: "memory");
    else if (rem == 1) asm volatile("s_waitcnt vmcnt(4)" ::: "memory");
    else               asm volatile("s_waitcnt vmcnt(0)" ::: "memory");
    __builtin_amdgcn_s_barrier();
    compute(cur);
    __builtin_amdgcn_s_barrier();
    if (t + 3 < NT) stage(cur, (t + 3) * 32);
    cur = cur + 1; if (cur == 3) cur = 0;
  }

  int rbase = (lane >> 4) * 4;
#pragma unroll
  for (int mt = 0; mt < 4; ++mt)
#pragma unroll
    for (int nt = 0; nt < 4; ++nt)
#pragma unroll
      for (int i = 0; i < 4; ++i) {
        int row = m0 + wm + mt * 16 + rbase + i;
        int col = n0 + wn + nt * 16 + ml;
        if (row >= M) continue;
        float v = acc[mt][nt][i] + bias[col];
        if (MODE == 1) {
          outB[(size_t)row * ldc + col] = __float2bfloat16(v);
        } else if (MODE == 5) {
          int b = row / Tp;
          int t2 = row - b * Tp;
          int i2 = t2 + shift; if (i2 >= Tp) i2 -= Tp;
          if (i2 < Tn)
            outB[((size_t)b * Tn + i2) * ldc + coff + col] = __float2bfloat16(v);
        }
      }
  (void)outF; (void)resid;
}

// ======================= 256x256 8-phase GEMM (big shapes) ==================
// m201-style schedule in plain HIP. BM=BN=256, BK=64 (2 khalves of 32), 8 waves
// (2Mx4N), per-wave C = 128x64 (acc[8][4]). LDS 128 KiB: [2 dbuf][2 khalf] per
// operand, 256x32 bf16 each. Per K-tile group: 4 phases
//   q0: stage B1(g+1); vmcnt(10); bar; 12 ds_read (A kh0 + B kh0); 16 MFMA ch0; bar
//   q1: stage A0(g+2); bar;                                   16 MFMA ch1; bar
//   q2: stage B0(g+2); vmcnt(10); bar; 12 ds_read (kh1);      16 MFMA ch0; bar
//   q3: stage A1(g+2); bar;                                   16 MFMA ch1; bar
// Counted vmcnt never drains to 0 until the tail (10/10 -> 10/8 -> 4/0).
// LDS chunk swizzle: phys_chunk = chunk ^ ((row>>1)&3), staged via inverse-
// swizzled GLOBAL source (LDS dest linear, as global_load_lds requires).
// Requires: M%256==0, N%256==0, K%64==0, K/64 >= 4.
// MODE 0: fp32 out   MODE 2: fp32 out=acc+bias+resid   MODE 3: bf16 gelu out
template <int MODE>
__global__ __launch_bounds__(512, 2) void gemm256_kernel(
    const bf16* __restrict__ A, const bf16* __restrict__ Wt,
    const float* __restrict__ bias,
    float* outF, bf16* outB, const float* resid,
    int M, int N, int K, int ldc) {
  __shared__ unsigned short sA[2][2][256 * 32];
  __shared__ unsigned short sB[2][2][256 * 32];
  int tid = threadIdx.x;
  int wave = tid >> 6, lane = tid & 63;

  // T1: bijective XCD swizzle
  int nx = gridDim.x;
  int nwg = nx * gridDim.y;
  int id = blockIdx.y * nx + blockIdx.x;
  int q8 = nwg >> 3, r8 = nwg & 7;
  int xcd = id & 7, pos = id >> 3;
  int swzid = (xcd < r8 ? xcd * (q8 + 1) : r8 * (q8 + 1) + (xcd - r8) * q8) + pos;
  int bx = swzid % nx, by = swzid / nx;
  int m0 = by * 256, n0 = bx * 256;

  int wr = wave >> 2, wc = wave & 3;  // 2 x 4 wave grid
  int ml = lane & 15;
  f32x4_t acc[8][4] = {};

  // ---- staging source precompute (inverse chunk swizzle on global col) ----
  // LDS slot layout: [256 rows][32 k], 64B rows, 4x 16B chunks per row.
  // wave w, load j covers slot rows [ (w*2+j)*16, +16 ); lane l -> row +(l>>2),
  // phys chunk l&3.  Source col chunk = (l&3) ^ ((l>>3)&3)  (= chunk^((row>>1)&3)).
  int rowoff0 = (wave * 2 + 0) * 16 + (lane >> 2);
  int rowoff1 = (wave * 2 + 1) * 16 + (lane >> 2);
  int gcol = ((lane & 3) ^ ((lane >> 3) & 3)) << 3;
  const bf16* pA0 = A + (size_t)(m0 + rowoff0) * K + gcol;
  const bf16* pA1 = A + (size_t)(m0 + rowoff1) * K + gcol;
  const bf16* pB0 = Wt + (size_t)(n0 + rowoff0) * K + gcol;
  const bf16* pB1 = Wt + (size_t)(n0 + rowoff1) * K + gcol;
  unsigned dst = (unsigned)(wave * 2) * 512;  // elems; j adds 512

  // ---- fragment read bases (swizzled): phys_chunk = (lane>>4) ^ ((ml>>1)&3) --
  int pc = ((lane >> 4) ^ ((ml >> 1) & 3)) & 3;
  int baseA = (wr * 128 + ml) * 32 + pc * 8;
  int baseB = (wc * 64 + ml) * 32 + pc * 8;

  auto stageA = [&](int kt, int kh) {
    int ko = kt * 64 + kh * 32;
    gload_lds16(pA0 + ko, &sA[kt & 1][kh][dst]);
    gload_lds16(pA1 + ko, &sA[kt & 1][kh][dst + 512]);
  };
  auto stageB = [&](int kt, int kh) {
    int ko = kt * 64 + kh * 32;
    gload_lds16(pB0 + ko, &sB[kt & 1][kh][dst]);
    gload_lds16(pB1 + ko, &sB[kt & 1][kh][dst + 512]);
  };

  bf16x8_t fa[8], fb[4];
  auto loadfrags = [&](int cur, int kh) {
    const unsigned short* mA = &sA[cur][kh][0];
    const unsigned short* mB = &sB[cur][kh][0];
#pragma unroll
    for (int rf = 0; rf < 8; ++rf)
      fa[rf] = *reinterpret_cast<const bf16x8_t*>(&mA[baseA + rf * 512]);
#pragma unroll
    for (int cf = 0; cf < 4; ++cf)
      fb[cf] = *reinterpret_cast<const bf16x8_t*>(&mB[baseB + cf * 512]);
  };
  auto mfma8x2 = [&](auto chc) {
    constexpr int CH = decltype(chc)::value;
    __builtin_amdgcn_s_setprio(1);
#pragma unroll
    for (int cf = 0; cf < 2; ++cf)
#pragma unroll
      for (int rf = 0; rf < 8; ++rf)
        acc[rf][CH * 2 + cf] = __builtin_amdgcn_mfma_f32_16x16x32_bf16(
            fa[rf], fb[CH * 2 + cf], acc[rf][CH * 2 + cf], 0, 0, 0);
    __builtin_amdgcn_s_setprio(0);
  };
  using C0 = std::integral_constant<int, 0>;
  using C1 = std::integral_constant<int, 1>;

  int KT = K >> 6;
  // prologue: ktile0 fully, ktile1 minus B.kh1 (staged at g0.q0)
  stageA(0, 0); stageB(0, 0); stageA(0, 1); stageB(0, 1);
  stageA(1, 0); stageB(1, 0); stageA(1, 1);

  for (int g = 0; g < KT; ++g) {
    int cur = g & 1;
    // ---------------- phase q0 ----------------
    if (g + 1 < KT) stageB(g + 1, 1);
    if (g == KT - 1) { asm volatile("s_waitcnt vmcnt(4)" ::: "memory"); }
    else             { asm volatile("s_waitcnt vmcnt(10)" ::: "memory"); }
    __builtin_amdgcn_s_barrier();
    asm volatile("" ::: "memory");
    loadfrags(cur, 0);
    mfma8x2(C0{});
    __builtin_amdgcn_s_barrier();
    // ---------------- phase q1 ----------------
    if (g + 2 < KT) stageA(g + 2, 0);
    __builtin_amdgcn_s_barrier();
    mfma8x2(C1{});
    __builtin_amdgcn_s_barrier();
    // ---------------- phase q2 ----------------
    if (g + 2 < KT) stageB(g + 2, 0);
    if (g < KT - 2)       { asm volatile("s_waitcnt vmcnt(10)" ::: "memory"); }
    else if (g == KT - 2) { asm volatile("s_waitcnt vmcnt(8)" ::: "memory"); }
    else                  { asm volatile("s_waitcnt vmcnt(0)" ::: "memory"); }
    __builtin_amdgcn_s_barrier();
    asm volatile("" ::: "memory");
    loadfrags(cur, 1);
    mfma8x2(C0{});
    __builtin_amdgcn_s_barrier();
    // ---------------- phase q3 ----------------
    if (g + 2 < KT) stageA(g + 2, 1);
    __builtin_amdgcn_s_barrier();
    mfma8x2(C1{});
    __builtin_amdgcn_s_barrier();
  }

  // ---------------- epilogue ----------------
  int rbase = (lane >> 4) * 4;
#pragma unroll
  for (int rf = 0; rf < 8; ++rf)
#pragma unroll
    for (int cf = 0; cf < 4; ++cf)
#pragma unroll
      for (int i = 0; i < 4; ++i) {
        int row = m0 + wr * 128 + rf * 16 + rbase + i;
        int col = n0 + wc * 64 + cf * 16 + ml;
        float v = acc[rf][cf][i] + bias[col];
        if (MODE == 0) {
          outF[(size_t)row * ldc + col] = v;
        } else if (MODE == 2) {
          outF[(size_t)row * ldc + col] = v + resid[(size_t)row * ldc + col];
        } else if (MODE == 3) {
          v = 0.5f * v * (1.0f + erff(v * 0.70710678118654752f));
          outB[(size_t)row * ldc + col] = __float2bfloat16(v);
        }
      }
  (void)M; (void)N;
}

extern "C" void kernel_launch(void* const* d_in, const int* in_sizes, int n_in,
                              void* d_out, int out_size, void* d_ws, size_t ws_size,
                              hipStream_t stream) {
  const float* x       = (const float*)d_in[0];
  const float* down_w  = (const float*)d_in[1];
  const float* down_b  = (const float*)d_in[2];
  const float* up_w    = (const float*)d_in[3];
  const float* up_b    = (const float*)d_in[4];
  const float* norm1_w = (const float*)d_in[5];
  const float* norm2_w = (const float*)d_in[6];
  const float* qkv1_w  = (const float*)d_in[7];
  const float* qkv1_b  = (const float*)d_in[8];
  const float* proj1_w = (const float*)d_in[9];
  const float* proj1_b = (const float*)d_in[10];
  const float* rpb1    = (const float*)d_in[11];
  const float* qkv2_w  = (const float*)d_in[12];
  const float* qkv2_b  = (const float*)d_in[13];
  const float* proj2_w = (const float*)d_in[14];
  const float* proj2_b = (const float*)d_in[15];
  const float* rpb2    = (const float*)d_in[16];
  const float* ffn_w1  = (const float*)d_in[17];
  const float* ffn_b1  = (const float*)d_in[18];
  const float* ffn_w2  = (const float*)d_in[19];
  const float* ffn_b2  = (const float*)d_in[20];
  float* out = (float*)d_out;

  const int Bb = 8, T = 4096, DIM = 1024, DIM_IN = 512;
  const int Tp = 4100, Tn = T;
  const int M  = Bb * T;   // 32768
  const int Mp = Bb * Tp;  // 32800
  const int nW1 = Tp / 10, nW2 = Tp / 20;

  char* ws = (char*)d_ws;
  const size_t MB = 1ull << 20;
  size_t wo = 0;
  auto walloc = [&](size_t elems) {
    bf16* p = (bf16*)(ws + wo);
    wo += ((elems * 2 + 255) & ~(size_t)255);
    return p;
  };
  bf16* w_down  = walloc(1024 * 512);
  bf16* w_up    = walloc(512 * 1024);
  bf16* w_qkv1  = walloc(256 * 768);
  bf16* w_proj1 = walloc(256 * 256);
  bf16* w_qkv2  = walloc(256 * 768);
  bf16* w_proj2 = walloc(256 * 256);
  bf16* w_ffn1  = walloc(1024 * 2048);
  bf16* w_ffn2  = walloc(2048 * 1024);
  bf16*  xbf     = (bf16*)(ws + 12 * MB);
  bf16*  xb1     = (bf16*)(ws + 12 * MB);
  bf16*  xb2     = (bf16*)(ws + 29 * MB);
  bf16*  att1    = (bf16*)(ws + 46 * MB);
  bf16*  att2    = (bf16*)(ws + 63 * MB);
  float* y1      = (float*)(ws + 80 * MB);
  bf16*  concatb = (bf16*)(ws + 80 * MB);
  bf16*  hbuf    = (bf16*)(ws + 80 * MB);
  bf16*  xi      = (bf16*)(ws + 144 * MB);
  bf16*  qkv1buf = (bf16*)(ws + 176 * MB);
  bf16*  qkv2buf = (bf16*)(ws + 225 * MB);
  bf16*  gbuf    = (bf16*)(ws + 144 * MB);

  auto cvt = [&](const float* src, bf16* dst, size_t n) {
    int grid = (int)((n / 4 + 255) / 256);
    hipLaunchKernelGGL(f2b_kernel, dim3(grid), dim3(256), 0, stream, src, dst, n);
  };
  auto tr = [&](const float* src, bf16* dst, int K, int N) {
    hipLaunchKernelGGL(transpose_f2b_kernel, dim3(N / 32, K / 32), dim3(256), 0, stream,
                       src, dst, K, N);
  };
  cvt(x, xbf, (size_t)M * DIM);
  tr(down_w, w_down, 1024, 512);
  tr(up_w, w_up, 512, 1024);
  tr(qkv1_w, w_qkv1, 256, 768);
  tr(proj1_w, w_proj1, 256, 256);
  tr(qkv2_w, w_qkv2, 256, 768);
  tr(proj2_w, w_proj2, 256, 256);
  tr(ffn_w1, w_ffn1, 1024, 2048);
  tr(ffn_w2, w_ffn2, 2048, 1024);

  auto gemm = [&](auto modeTag, const bf16* A, const bf16* Wt, const float* bias,
                  float* oF, bf16* oB, const float* res,
                  int Mm, int Nn, int Kk, int ldc, int tp, int tn, int sh, int co) {
    constexpr int MODE = decltype(modeTag)::value;
    hipLaunchKernelGGL((gemm_kernel<MODE>), dim3(Nn / 128, (Mm + 127) / 128), dim3(256), 0,
                       stream, A, Wt, bias, oF, oB, res, Mm, Nn, Kk, ldc, tp, tn, sh, co);
  };
  auto gemm256 = [&](auto modeTag, const bf16* A, const bf16* Wt, const float* bias,
                     float* oF, bf16* oB, const float* res, int Mm, int Nn, int Kk, int ldc) {
    constexpr int MODE = decltype(modeTag)::value;
    hipLaunchKernelGGL((gemm256_kernel<MODE>), dim3(Nn / 256, Mm / 256), dim3(512), 0,
                       stream, A, Wt, bias, oF, oB, res, Mm, Nn, Kk, ldc);
  };
  using I0 = std::integral_constant<int, 0>;
  using I1 = std::integral_constant<int, 1>;
  using I2 = std::integral_constant<int, 2>;
  using I3 = std::integral_constant<int, 3>;
  using I5 = std::integral_constant<int, 5>;

  // down: y1 = x @ down_w + down_b (fp32)
  gemm256(I0{}, xbf, w_down, down_b, y1, nullptr, nullptr, M, DIM_IN, DIM, DIM_IN);
  hipLaunchKernelGGL(rmsnorm_kernel, dim3(M), dim3(256), 0, stream, y1, norm1_w, xi, DIM_IN);
  hipLaunchKernelGGL(gather_kernel, dim3(Mp), dim3(256), 0, stream, xi, xb1, Tp, Tn, 5, 0);
  hipLaunchKernelGGL(gather_kernel, dim3(Mp), dim3(256), 0, stream, xi, xb2, Tp, Tn, 10, 256);
  gemm(I1{}, xb1, w_qkv1, qkv1_b, nullptr, qkv1buf, nullptr, Mp, 768, 256, 768, 0, 0, 0, 0);
  gemm(I1{}, xb2, w_qkv2, qkv2_b, nullptr, qkv2buf, nullptr, Mp, 768, 256, 768, 0, 0, 0, 0);
  hipLaunchKernelGGL((attn_kernel<10, 5>), dim3(Bb * nW1), dim3(128), 0, stream,
                     qkv1buf, rpb1, att1, nW1, Tp);
  hipLaunchKernelGGL((attn_kernel<20, 10>), dim3(Bb * nW2), dim3(192), 0, stream,
                     qkv2buf, rpb2, att2, nW2, Tp);
  gemm(I5{}, att1, w_proj1, proj1_b, nullptr, concatb, nullptr, Mp, 256, 256, 512, Tp, Tn, 5, 0);
  gemm(I5{}, att2, w_proj2, proj2_b, nullptr, concatb, nullptr, Mp, 256, 256, 512, Tp, Tn, 10, 256);
  // up: out = x + concat @ up_w + up_b (fp32)
  gemm256(I2{}, concatb, w_up, up_b, out, nullptr, x, M, DIM, DIM_IN, DIM);
  hipLaunchKernelGGL(rmsnorm_kernel, dim3(M), dim3(256), 0, stream, out, norm2_w, hbuf, DIM);
  gemm256(I3{}, hbuf, w_ffn1, ffn_b1, nullptr, gbuf, nullptr, M, 2048, DIM, 2048);
  gemm256(I2{}, gbuf, w_ffn2, ffn_b2, out, nullptr, out, M, DIM, 2048, DIM);
  (void)in_sizes; (void)n_in; (void)out_size; (void)ws_size;
}